// Round 7
// baseline (502.073 us; speedup 1.0000x reference)
//
#include <hip/hip_runtime.h>

typedef unsigned short u16;
typedef __bf16 bf16x8 __attribute__((ext_vector_type(8)));
typedef float f32x4 __attribute__((ext_vector_type(4)));
typedef unsigned short u16x8 __attribute__((ext_vector_type(8)));

static __device__ __forceinline__ float bf2f(u16 u) {
    return __uint_as_float(((unsigned)u) << 16);
}
static __device__ __forceinline__ u16 f2bf(float f) {
    unsigned u = __float_as_uint(f);
    unsigned r = (u + 0x7FFFu + ((u >> 16) & 1u)) >> 16;
    return (u16)r;
}

// ---- edge_index word-stride detection: int32-packed (1) vs int64-as-2-words (2)
__global__ void detect_kernel(const int* __restrict__ ei, int* __restrict__ flag) {
    if (blockIdx.x == 0 && threadIdx.x == 0) {
        int zc = 0;
        for (int t = 0; t < 64; ++t) zc += (ei[2 * t + 1] == 0) ? 1 : 0;
        *flag = (zc >= 60) ? 2 : 1;
    }
}
static __device__ __forceinline__ int ld_idx(const int* ei, int pos, int st, int N) {
    int v = ei[(size_t)pos * (size_t)st];
    return v < 0 ? 0 : (v >= N ? N - 1 : v);
}

// ---- per-XCD privatized histogram: WG w increments copy (w&7) only ->
// each line of copy x is owned by XCD x's L2; edge list read once.
__global__ __launch_bounds__(256) void hist_xcd(const int* __restrict__ ei,
                                                const int* __restrict__ flag,
                                                int* __restrict__ deg8, int E, int ET, int N,
                                                int nwg) {
    const int st = *flag;
    int* deg = deg8 + (size_t)(blockIdx.x & 7) * N;
    const int stride = nwg * 256;
    for (int j = blockIdx.x * 256 + (int)threadIdx.x; j < ET; j += stride) {
        int d = (j < E) ? ld_idx(ei, E + j, st, N) : (j - E);
        atomicAdd(&deg[d], 1);
    }
}

// ================= CSR scan (rowptr from 8-way privatized deg) ===============
#define SCHUNK 4096
__global__ void scan_reduce_kernel(const int* __restrict__ deg8, int* __restrict__ bsum,
                                   int N) {
    __shared__ int sdata[256];
    int t = threadIdx.x;
    int base = blockIdx.x * SCHUNK + t * 16;
    int s = 0;
#pragma unroll
    for (int j = 0; j < 16; ++j) {
        int i = base + j;
        if (i < N) {
#pragma unroll
            for (int c = 0; c < 8; ++c) s += deg8[(size_t)c * N + i];
        }
    }
    sdata[t] = s;
    __syncthreads();
    for (int o = 128; o > 0; o >>= 1) {
        if (t < o) sdata[t] += sdata[t + o];
        __syncthreads();
    }
    if (t == 0) bsum[blockIdx.x] = sdata[0];
}
__global__ void scan_mid_kernel(int* __restrict__ bsum, int nb) {
    if (threadIdx.x == 0 && blockIdx.x == 0) {
        int run = 0;
        for (int b = 0; b < nb; ++b) { int v = bsum[b]; bsum[b] = run; run += v; }
    }
}
__global__ void scan_final_kernel(const int* __restrict__ deg8, const int* __restrict__ bsum,
                                  int* __restrict__ rowptr, int* __restrict__ cursor, int N,
                                  int ET) {
    __shared__ int sdata[256];
    int t = threadIdx.x;
    int base = blockIdx.x * SCHUNK + t * 16;
    int v[16];
    int s = 0;
#pragma unroll
    for (int j = 0; j < 16; ++j) {
        int i = base + j;
        int d = 0;
        if (i < N) {
#pragma unroll
            for (int c = 0; c < 8; ++c) d += deg8[(size_t)c * N + i];
        }
        v[j] = d;
        s += d;
    }
    sdata[t] = s;
    __syncthreads();
    for (int o = 1; o < 256; o <<= 1) {
        int add = (t >= o) ? sdata[t - o] : 0;
        __syncthreads();
        sdata[t] += add;
        __syncthreads();
    }
    int excl = (t == 0) ? 0 : sdata[t - 1];
    int off = bsum[blockIdx.x] + excl;
#pragma unroll
    for (int j = 0; j < 16; ++j) {
        int i = base + j;
        if (i < N) {
            rowptr[i] = off;
            cursor[i] = off;
            off += v[j];
        }
    }
    if (blockIdx.x == 0 && t == 0) rowptr[N] = ET;
}

// ---- XCD-sliced scatter: group x = blockIdx%8 exclusively owns dst slice x.
__global__ __launch_bounds__(256) void scatter_xcd(const int* __restrict__ ei,
                                                   const int* __restrict__ flag,
                                                   int* __restrict__ cursor,
                                                   int* __restrict__ col, int E, int ET, int N,
                                                   int nwg) {
    const int st = *flag;
    const int x = blockIdx.x & 7;
    const int wgx = blockIdx.x >> 3;
    const int perx = nwg >> 3;
    const int Np = (N + 7) >> 3;
    const int lo = x * Np;
    const int hi = (lo + Np < N) ? lo + Np : N;
    const int stride = perx * 256;
    for (int j = wgx * 256 + (int)threadIdx.x; j < ET; j += stride) {
        int d = (j < E) ? ld_idx(ei, E + j, st, N) : (j - E);
        if (d >= lo && d < hi) {
            int s = (j < E) ? ld_idx(ei, j, st, N) : d;
            int pos = atomicAdd(&cursor[d], 1);
            col[pos] = s;
        }
    }
}

// ---------------- fused GEMM: C[M,NC] = A[M,128] @ W[128,NC]
// MFMA 16x16x32 bf16. A: A[m=lane&15][k=quad*8+j]; B: B[k=quad*8+j][n=lane&15];
// D: col=lane&15, row=quad*4+reg. W (f32) -> register-resident bf16 frags.
// EPI 1: store C bf16 + per-row scores (s_src,s_dst) via quad-lane reduction.
// EPI 2: no C store; fused log_softmax over NC=64 cols -> outp f32.
template <int NC, bool AF32, int EPI>
__global__ __launch_bounds__(256) void gemm_fused(
    const void* __restrict__ Ap, const float* __restrict__ W, u16* __restrict__ Cout, int M,
    const float* __restrict__ av_s, const float* __restrict__ av_d, float* __restrict__ ssrc,
    float* __restrict__ sdst, const float* __restrict__ bl, float* __restrict__ outp,
    int G1) {
    const int lane = threadIdx.x & 63;
    const int quad = lane >> 4;
    const int r = lane & 15;
    const int gw = (blockIdx.x * 256 + threadIdx.x) >> 6;
    const int nw = G1 * 4;

    bf16x8 bf[NC / 16][4];
#pragma unroll
    for (int nt = 0; nt < NC / 16; ++nt)
#pragma unroll
        for (int kk = 0; kk < 4; ++kk) {
            union { bf16x8 v; u16 s[8]; } u;
#pragma unroll
            for (int j = 0; j < 8; ++j)
                u.s[j] = f2bf(W[(size_t)(kk * 32 + quad * 8 + j) * NC + nt * 16 + r]);
            bf[nt][kk] = u.v;
        }
    float avs[NC / 16], avd[NC / 16], blv[NC / 16];
    if (EPI == 1) {
#pragma unroll
        for (int nt = 0; nt < NC / 16; ++nt) {
            avs[nt] = av_s[nt * 16 + r];
            avd[nt] = av_d[nt * 16 + r];
        }
    }
    if (EPI == 2) {
#pragma unroll
        for (int nt = 0; nt < NC / 16; ++nt) blv[nt] = bl[nt * 16 + r];
    }

    const int ntiles = (M + 15) >> 4;
    for (int t = gw; t < ntiles; t += nw) {
        const int row0 = t << 4;
        bf16x8 af[4];
        if (AF32) {
            const float* arow = (const float*)Ap + (size_t)(row0 + r) * 128;
#pragma unroll
            for (int kk = 0; kk < 4; ++kk) {
                f32x4 f0 = *reinterpret_cast<const f32x4*>(arow + kk * 32 + quad * 8);
                f32x4 f1 = *reinterpret_cast<const f32x4*>(arow + kk * 32 + quad * 8 + 4);
                union { bf16x8 v; u16 s[8]; } u;
#pragma unroll
                for (int j = 0; j < 4; ++j) { u.s[j] = f2bf(f0[j]); u.s[4 + j] = f2bf(f1[j]); }
                af[kk] = u.v;
            }
        } else {
            const u16* arow = (const u16*)Ap + (size_t)(row0 + r) * 128;
#pragma unroll
            for (int kk = 0; kk < 4; ++kk)
                af[kk] = *reinterpret_cast<const bf16x8*>(arow + kk * 32 + quad * 8);
        }
        f32x4 acc[NC / 16];
#pragma unroll
        for (int nt = 0; nt < NC / 16; ++nt) acc[nt] = (f32x4){0.f, 0.f, 0.f, 0.f};
#pragma unroll
        for (int kk = 0; kk < 4; ++kk)
#pragma unroll
            for (int nt = 0; nt < NC / 16; ++nt)
                acc[nt] = __builtin_amdgcn_mfma_f32_16x16x32_bf16(af[kk], bf[nt][kk],
                                                                  acc[nt], 0, 0, 0);
        if (EPI != 2) {
#pragma unroll
            for (int nt = 0; nt < NC / 16; ++nt)
#pragma unroll
                for (int reg = 0; reg < 4; ++reg)
                    Cout[(size_t)(row0 + quad * 4 + reg) * NC + nt * 16 + r] =
                        f2bf(acc[nt][reg]);
        }
        if (EPI == 1) {
            float ps[4] = {0.f, 0.f, 0.f, 0.f}, pd[4] = {0.f, 0.f, 0.f, 0.f};
#pragma unroll
            for (int nt = 0; nt < NC / 16; ++nt)
#pragma unroll
                for (int reg = 0; reg < 4; ++reg) {
                    ps[reg] += acc[nt][reg] * avs[nt];
                    pd[reg] += acc[nt][reg] * avd[nt];
                }
#pragma unroll
            for (int o = 1; o < 16; o <<= 1)
#pragma unroll
                for (int reg = 0; reg < 4; ++reg) {
                    ps[reg] += __shfl_xor(ps[reg], o);
                    pd[reg] += __shfl_xor(pd[reg], o);
                }
            if (r == 0) {
#pragma unroll
                for (int reg = 0; reg < 4; ++reg) {
                    ssrc[row0 + quad * 4 + reg] = ps[reg];
                    sdst[row0 + quad * 4 + reg] = pd[reg];
                }
            }
        }
        if (EPI == 2) {
#pragma unroll
            for (int reg = 0; reg < 4; ++reg) {
                float v[NC / 16];
                float m = -3.4e38f;
#pragma unroll
                for (int nt = 0; nt < NC / 16; ++nt) {
                    v[nt] = acc[nt][reg] + blv[nt];
                    m = fmaxf(m, v[nt]);
                }
#pragma unroll
                for (int o = 1; o < 16; o <<= 1) m = fmaxf(m, __shfl_xor(m, o));
                float s = 0.f;
#pragma unroll
                for (int nt = 0; nt < NC / 16; ++nt) s += __expf(v[nt] - m);
#pragma unroll
                for (int o = 1; o < 16; o <<= 1) s += __shfl_xor(s, o);
                float L = __logf(s);
                const size_t rb = (size_t)(row0 + quad * 4 + reg) * NC;
#pragma unroll
                for (int nt = 0; nt < NC / 16; ++nt)
                    outp[rb + nt * 16 + r] = v[nt] - m - L;
            }
        }
    }
}

// ---------------- fused denom+agg over CSR: 16-lane group per dst node.
// pass A: denom = sum(exp(leaky(score))); pass B: weighted gather-accumulate.
// MODE 1: out = relu(acc + b).  MODE 2: out = acc + b + skip.
template <int MODE>
__global__ __launch_bounds__(256) void agg_fused(
    const int* __restrict__ rowptr, const int* __restrict__ col,
    const float* __restrict__ ssrc, const float* __restrict__ sdst,
    const u16* __restrict__ h, const float* __restrict__ b, const u16* __restrict__ skip,
    u16* __restrict__ out, int N) {
    const int lane = threadIdx.x & 63;
    const int gwave = (blockIdx.x * 256 + threadIdx.x) >> 6;
    const int grp = lane >> 4;
    const int ln = lane & 15;
    const int i = gwave * 4 + grp;
    if (i >= N) return;
    const int start = rowptr[i], end = rowptr[i + 1];
    const float sd = sdst[i];
    float sm = 0.f;
    for (int e = start + ln; e < end; e += 16) {
        float sc = ssrc[col[e]] + sd;
        sc = sc > 0.f ? sc : 0.2f * sc;
        sm += __expf(fminf(sc, 60.f));
    }
#pragma unroll
    for (int o = 1; o < 16; o <<= 1) sm += __shfl_xor(sm, o);
    const float rd = 1.f / sm;

    const size_t coff = (size_t)ln * 8;
    float acc[8] = {0.f, 0.f, 0.f, 0.f, 0.f, 0.f, 0.f, 0.f};
    int e = start;
    for (; e + 2 <= end; e += 2) {
        int c0 = col[e], c1 = col[e + 1];
        float s0 = ssrc[c0] + sd;
        float s1 = ssrc[c1] + sd;
        s0 = s0 > 0.f ? s0 : 0.2f * s0;
        s1 = s1 > 0.f ? s1 : 0.2f * s1;
        float w0 = __expf(fminf(s0, 60.f)) * rd;
        float w1 = __expf(fminf(s1, 60.f)) * rd;
        u16x8 r0 = *reinterpret_cast<const u16x8*>(h + (size_t)c0 * 128 + coff);
        u16x8 r1 = *reinterpret_cast<const u16x8*>(h + (size_t)c1 * 128 + coff);
#pragma unroll
        for (int j = 0; j < 8; ++j) acc[j] += w0 * bf2f(r0[j]) + w1 * bf2f(r1[j]);
    }
    if (e < end) {
        int c0 = col[e];
        float s0 = ssrc[c0] + sd;
        s0 = s0 > 0.f ? s0 : 0.2f * s0;
        float w0 = __expf(fminf(s0, 60.f)) * rd;
        u16x8 r0 = *reinterpret_cast<const u16x8*>(h + (size_t)c0 * 128 + coff);
#pragma unroll
        for (int j = 0; j < 8; ++j) acc[j] += w0 * bf2f(r0[j]);
    }
    u16x8 o;
    if (MODE == 1) {
#pragma unroll
        for (int j = 0; j < 8; ++j) {
            float v = acc[j] + b[coff + j];
            v = v > 0.f ? v : 0.f;
            o[j] = f2bf(v);
        }
    } else {
        const u16x8 sk = *reinterpret_cast<const u16x8*>(skip + (size_t)i * 128 + coff);
#pragma unroll
        for (int j = 0; j < 8; ++j) {
            float v = acc[j] + b[coff + j] + bf2f(sk[j]);
            o[j] = f2bf(v);
        }
    }
    *reinterpret_cast<u16x8*>(out + (size_t)i * 128 + coff) = o;
}

// ---------------- echo edge_index as f32 (output 1)
__global__ void copy_ei_kernel(const int* __restrict__ ei, const int* __restrict__ flag,
                               float* __restrict__ out, int n, int N) {
    int j = blockIdx.x * 256 + threadIdx.x;
    if (j < n) out[j] = (float)ld_idx(ei, j, *flag, N);
}

extern "C" void kernel_launch(void* const* d_in, const int* in_sizes, int n_in, void* d_out,
                              int out_size, void* d_ws, size_t ws_size, hipStream_t stream) {
    int ix = 0, iei = 1;
    if (in_sizes[0] < in_sizes[1]) { ix = 1; iei = 0; }
    const float* x = (const float*)d_in[ix];
    const int* ei = (const int*)d_in[iei];
    const float* W1 = (const float*)d_in[2];
    const float* a1s = (const float*)d_in[3];
    const float* a1d = (const float*)d_in[4];
    const float* b1 = (const float*)d_in[5];
    const float* W2 = (const float*)d_in[6];
    const float* a2s = (const float*)d_in[7];
    const float* a2d = (const float*)d_in[8];
    const float* b2 = (const float*)d_in[9];
    const float* Wl = (const float*)d_in[10];
    const float* bl = (const float*)d_in[11];

    const int N = in_sizes[ix] / 128;
    const int E = (out_size - N * 64) / 2;  // out = [logp N*64 | edge_index 2E], f32
    const int ET = E + N;

    char* ws = (char*)d_ws;
    size_t off = 0;
    auto alloc = [&](size_t bytes) {
        void* p = ws + off;
        off += (bytes + 255) & ~(size_t)255;
        return p;
    };
    u16* h = (u16*)alloc((size_t)N * 128 * 2);   // bf16 gemm out / gather source
    u16* h1 = (u16*)alloc((size_t)N * 128 * 2);  // bf16 layer-1 activation (skip input)
    u16* o2 = (u16*)alloc((size_t)N * 128 * 2);  // bf16 layer-2 out (final gemm input)
    float* ssrc = (float*)alloc((size_t)N * 4);
    float* sdst = (float*)alloc((size_t)N * 4);
    int* eflag = (int*)alloc(256);
    int* deg8 = (int*)alloc((size_t)8 * N * 4);  // per-XCD privatized histograms
    int* cursor = (int*)alloc((size_t)N * 4);
    int* rowptr = (int*)alloc((size_t)(N + 1) * 4);
    int* bsum = (int*)alloc(4096);
    int* colv = (int*)alloc((size_t)ET * 4);

    float* out_logp = (float*)d_out;
    float* out_ei = out_logp + (size_t)N * 64;

    dim3 blk(256);
    const int ngrid4 = (N + 15) / 16;  // 16-lane group per node, 16 nodes/block
    const int nb = (N + SCHUNK - 1) / SCHUNK;
    const int G1 = 512;  // gemm grid

    detect_kernel<<<1, 64, 0, stream>>>(ei, eflag);
    hipMemsetAsync(deg8, 0, (size_t)8 * N * 4, stream);

    // ---- histogram (per-XCD privatized copies; no cross-XCD line ping-pong) ----
    hist_xcd<<<1024, blk, 0, stream>>>(ei, eflag, deg8, E, ET, N, 1024);

    // ---- layer-1 GEMM (+scores epilogue) ----
    gemm_fused<128, true, 1><<<G1, blk, 0, stream>>>(x, W1, h, N, a1s, a1d, ssrc, sdst,
                                                     nullptr, nullptr, G1);

    // ---- CSR scan + XCD-sliced scatter ----
    scan_reduce_kernel<<<nb, blk, 0, stream>>>(deg8, bsum, N);
    scan_mid_kernel<<<1, 64, 0, stream>>>(bsum, nb);
    scan_final_kernel<<<nb, blk, 0, stream>>>(deg8, bsum, rowptr, cursor, N, ET);
    scatter_xcd<<<1024, blk, 0, stream>>>(ei, eflag, cursor, colv, E, ET, N, 1024);

    // ---- layer 1 aggregation (denom + weighted gather + relu/bias) ----
    agg_fused<1><<<ngrid4, blk, 0, stream>>>(rowptr, colv, ssrc, sdst, h, b1, nullptr, h1, N);

    // ---- layer 2 ----
    gemm_fused<128, false, 1><<<G1, blk, 0, stream>>>(h1, W2, h, N, a2s, a2d, ssrc, sdst,
                                                      nullptr, nullptr, G1);
    agg_fused<2><<<ngrid4, blk, 0, stream>>>(rowptr, colv, ssrc, sdst, h, b2, h1, o2, N);

    // ---- final linear with fused log_softmax ----
    gemm_fused<64, false, 2><<<G1, blk, 0, stream>>>(o2, Wl, nullptr, N, nullptr, nullptr,
                                                     nullptr, nullptr, bl, out_logp, G1);

    copy_ei_kernel<<<(2 * E + 255) / 256, blk, 0, stream>>>(ei, eflag, out_ei, 2 * E, N);
}